// Round 1
// baseline (333.350 us; speedup 1.0000x reference)
//
#include <hip/hip_runtime.h>
#include <stdint.h>

typedef __attribute__((ext_vector_type(4))) float f32x4;
typedef __attribute__((ext_vector_type(8))) __bf16 bf16x8v;

#define E_DIM 1024
#define H_NUM 16
#define D_DIM 64
#define SQ_LEN 2048
#define SKV_LEN 4096

static __device__ __forceinline__ unsigned short f2bf(float f) {
  union { float f; unsigned u; } v; v.f = f;
  unsigned u = v.u;
  u += 0x7fffu + ((u >> 16) & 1u);
  return (unsigned short)(u >> 16);
}

static __device__ __forceinline__ void gload_lds16(const unsigned short* g, unsigned short* l) {
  __builtin_amdgcn_global_load_lds(
      (const __attribute__((address_space(1))) unsigned int*)g,
      (__attribute__((address_space(3))) unsigned int*)l,
      16, 0, 0);
}

__global__ void convert_kernel(const float* __restrict__ in, unsigned short* __restrict__ out, int n) {
  int i = (blockIdx.x * blockDim.x + threadIdx.x) * 4;
  if (i >= n) return;
  const float4 f = *reinterpret_cast<const float4*>(in + i);
  ushort4 o;
  o.x = f2bf(f.x); o.y = f2bf(f.y); o.z = f2bf(f.z); o.w = f2bf(f.w);
  *reinterpret_cast<ushort4*>(out + i) = o;
}

// C[m][n] = sum_k A[m][k] * W[n][k]  (torch y = x @ W.T), 128x128 tile, BK=64.
// job 0: Q from x rows (M=4096), scaled by 0.125, out [B,H,SQ,D]
// job 1: K from concat(cache,x) rows (M=8192), out [B,H,SKV,D]
// job 2: V same rows, out transposed [B,H,D,SKV]
__global__ __launch_bounds__(256)
void qkv_gemm(const unsigned short* __restrict__ xb,
              const unsigned short* __restrict__ cb,
              const unsigned short* __restrict__ wqkv,
              const float* __restrict__ in_b,
              unsigned short* __restrict__ Qo,
              unsigned short* __restrict__ Ko,
              unsigned short* __restrict__ Vo) {
  const int job = blockIdx.z;
  const int mt = blockIdx.x, nt = blockIdx.y;
  if (job == 0 && mt >= 32) return;

  __shared__ unsigned short As[128 * 64];
  __shared__ unsigned short Bs[128 * 64];

  const int t = threadIdx.x;
  const int lane = t & 63, wave = t >> 6;
  const int g = lane >> 4, lr = lane & 15;
  const int wr = (wave >> 1) * 64, wc = (wave & 1) * 64;
  const int m0 = mt * 128, n0 = nt * 128;

  const unsigned short* arow[4];
  const unsigned short* brow[4];
  int col[4];
  const unsigned short* wbase = wqkv + job * (E_DIM * E_DIM);
#pragma unroll
  for (int i = 0; i < 4; ++i) {
    int f = i * 256 + t;
    int row = f >> 3, grp = f & 7;
    int gm = m0 + row;
    const unsigned short* src;
    if (job == 0) {
      src = xb + gm * E_DIM;
    } else {
      int b = gm >> 12, s = gm & 4095;
      src = (s < 2048) ? (cb + (b * 2048 + s) * E_DIM)
                       : (xb + (b * 2048 + (s - 2048)) * E_DIM);
    }
    arow[i] = src;
    brow[i] = wbase + (n0 + row) * E_DIM;
    col[i] = (grp ^ (row & 7)) * 8;  // inverse-swizzled source granule (rule 21)
  }

  f32x4 acc[4][4];
#pragma unroll
  for (int i = 0; i < 4; ++i)
#pragma unroll
    for (int j = 0; j < 4; ++j) acc[i][j] = f32x4{0.f, 0.f, 0.f, 0.f};

  for (int k0 = 0; k0 < E_DIM; k0 += 64) {
#pragma unroll
    for (int i = 0; i < 4; ++i) {
      unsigned ldsoff = (unsigned)((i * 256 + wave * 64) * 16);
      gload_lds16(arow[i] + k0 + col[i], (unsigned short*)((char*)As + ldsoff));
      gload_lds16(brow[i] + k0 + col[i], (unsigned short*)((char*)Bs + ldsoff));
    }
    __syncthreads();
#pragma unroll
    for (int ks = 0; ks < 2; ++ks) {
      bf16x8v a[4], b[4];
#pragma unroll
      for (int mf = 0; mf < 4; ++mf) {
        int row = wr + mf * 16 + lr;
        unsigned byte = (unsigned)(row * 128 + ks * 64 + g * 16) ^ (unsigned)((row & 7) << 4);
        a[mf] = *reinterpret_cast<const bf16x8v*>((const char*)As + byte);
      }
#pragma unroll
      for (int nf = 0; nf < 4; ++nf) {
        int row = wc + nf * 16 + lr;
        unsigned byte = (unsigned)(row * 128 + ks * 64 + g * 16) ^ (unsigned)((row & 7) << 4);
        b[nf] = *reinterpret_cast<const bf16x8v*>((const char*)Bs + byte);
      }
#pragma unroll
      for (int mf = 0; mf < 4; ++mf)
#pragma unroll
        for (int nf = 0; nf < 4; ++nf)
          acc[mf][nf] = __builtin_amdgcn_mfma_f32_16x16x32_bf16(a[mf], b[nf], acc[mf][nf], 0, 0, 0);
    }
    __syncthreads();
  }

  const float* bptr = in_b + job * E_DIM;
#pragma unroll
  for (int mf = 0; mf < 4; ++mf) {
#pragma unroll
    for (int nf = 0; nf < 4; ++nf) {
      int n = n0 + wc + nf * 16 + lr;
      float bv = bptr[n];
      int h = n >> 6, d = n & 63;
#pragma unroll
      for (int r = 0; r < 4; ++r) {
        int m = m0 + wr + mf * 16 + g * 4 + r;
        float val = acc[mf][nf][r] + bv;
        if (job == 0) {
          int b = m >> 11, s = m & 2047;
          Qo[((b * H_NUM + h) * SQ_LEN + s) * D_DIM + d] = f2bf(val * 0.125f);
        } else if (job == 1) {
          int b = m >> 12, s = m & 4095;
          Ko[((b * H_NUM + h) * SKV_LEN + s) * D_DIM + d] = f2bf(val);
        } else {
          int b = m >> 12, s = m & 4095;
          Vo[((b * H_NUM + h) * D_DIM + d) * SKV_LEN + s] = f2bf(val);
        }
      }
    }
  }
}

// Flash attention. Per block: 128 q-rows (4 waves x 32), KV tiles of 64.
// Q pre-scaled by 1/sqrt(D). K: [B,H,SKV,D], V: [B,H,D,SKV] (transposed).
__global__ __launch_bounds__(256)
void attn_kernel(const unsigned short* __restrict__ Qb,
                 const unsigned short* __restrict__ Kb,
                 const unsigned short* __restrict__ Vb,
                 unsigned short* __restrict__ ctx) {
  const int qt = blockIdx.x;   // 16 q-tiles
  const int bh = blockIdx.y;   // 32 (b*16+h)

  __shared__ unsigned short Ks[64 * 64];
  __shared__ unsigned short Vs[64 * 64];
  __shared__ unsigned short Ps[4][32 * 64];

  const int t = threadIdx.x;
  const int lane = t & 63, wave = t >> 6;
  const int g = lane >> 4, lr = lane & 15;

  const unsigned short* Qh = Qb + (size_t)bh * SQ_LEN * D_DIM;
  const unsigned short* Kh = Kb + (size_t)bh * SKV_LEN * D_DIM;
  const unsigned short* Vh = Vb + (size_t)bh * D_DIM * SKV_LEN;

  const int q0 = qt * 128 + wave * 32;
  bf16x8v qf[2][2];
#pragma unroll
  for (int mf = 0; mf < 2; ++mf)
#pragma unroll
    for (int ks = 0; ks < 2; ++ks)
      qf[mf][ks] = *reinterpret_cast<const bf16x8v*>(Qh + (q0 + mf * 16 + lr) * D_DIM + ks * 32 + g * 8);

  f32x4 o[2][4];
  float mrow[2][4], lrow[2][4];
#pragma unroll
  for (int mf = 0; mf < 2; ++mf) {
#pragma unroll
    for (int nf = 0; nf < 4; ++nf) o[mf][nf] = f32x4{0.f, 0.f, 0.f, 0.f};
#pragma unroll
    for (int r = 0; r < 4; ++r) { mrow[mf][r] = -1e30f; lrow[mf][r] = 0.f; }
  }

  int srow[2], sgrp[2];
#pragma unroll
  for (int i = 0; i < 2; ++i) {
    int f = i * 256 + t;
    srow[i] = f >> 3;
    sgrp[i] = (f & 7) ^ (srow[i] & 7);
  }

  unsigned short* Pw = &Ps[wave][0];

  for (int kv0 = 0; kv0 < SKV_LEN; kv0 += 64) {
#pragma unroll
    for (int i = 0; i < 2; ++i) {
      unsigned ldsoff = (unsigned)((i * 256 + wave * 64) * 16);
      gload_lds16(Kh + (kv0 + srow[i]) * D_DIM + sgrp[i] * 8, (unsigned short*)((char*)Ks + ldsoff));
      gload_lds16(Vh + srow[i] * SKV_LEN + kv0 + sgrp[i] * 8, (unsigned short*)((char*)Vs + ldsoff));
    }
    __syncthreads();

    // S = Q @ K^T   (S[q][kv], C-layout: col=lane&15 -> kv, row=(lane>>4)*4+r -> q)
    f32x4 s[2][4];
#pragma unroll
    for (int mf = 0; mf < 2; ++mf)
#pragma unroll
      for (int nf = 0; nf < 4; ++nf) s[mf][nf] = f32x4{0.f, 0.f, 0.f, 0.f};
#pragma unroll
    for (int ks = 0; ks < 2; ++ks) {
      bf16x8v kf[4];
#pragma unroll
      for (int nf = 0; nf < 4; ++nf) {
        int row = nf * 16 + lr;
        unsigned byte = (unsigned)(row * 128 + ks * 64 + g * 16) ^ (unsigned)((row & 7) << 4);
        kf[nf] = *reinterpret_cast<const bf16x8v*>((const char*)Ks + byte);
      }
#pragma unroll
      for (int mf = 0; mf < 2; ++mf)
#pragma unroll
        for (int nf = 0; nf < 4; ++nf)
          s[mf][nf] = __builtin_amdgcn_mfma_f32_16x16x32_bf16(qf[mf][ks], kf[nf], s[mf][nf], 0, 0, 0);
    }

    // online softmax: row stats live per (mf, r), shared across 16-lane group
    float pmax[2][4];
#pragma unroll
    for (int mf = 0; mf < 2; ++mf)
#pragma unroll
      for (int r = 0; r < 4; ++r) {
        float mv = fmaxf(fmaxf(s[mf][0][r], s[mf][1][r]), fmaxf(s[mf][2][r], s[mf][3][r]));
        pmax[mf][r] = mv;
      }
#pragma unroll
    for (int mask = 1; mask < 16; mask <<= 1)
#pragma unroll
      for (int mf = 0; mf < 2; ++mf)
#pragma unroll
        for (int r = 0; r < 4; ++r)
          pmax[mf][r] = fmaxf(pmax[mf][r], __shfl_xor(pmax[mf][r], mask, 64));

    float fac[2][4];
#pragma unroll
    for (int mf = 0; mf < 2; ++mf)
#pragma unroll
      for (int r = 0; r < 4; ++r) {
        float mn = fmaxf(mrow[mf][r], pmax[mf][r]);
        fac[mf][r] = __expf(mrow[mf][r] - mn);
        mrow[mf][r] = mn;
      }

    float psum[2][4] = {{0.f, 0.f, 0.f, 0.f}, {0.f, 0.f, 0.f, 0.f}};
#pragma unroll
    for (int mf = 0; mf < 2; ++mf)
#pragma unroll
      for (int nf = 0; nf < 4; ++nf)
#pragma unroll
        for (int r = 0; r < 4; ++r) {
          float p = __expf(s[mf][nf][r] - mrow[mf][r]);
          psum[mf][r] += p;
          int q = mf * 16 + g * 4 + r;
          int kc = nf * 16 + lr;
          unsigned byte = (unsigned)(q * 128 + kc * 2) ^ (unsigned)((q & 7) << 4);
          *(unsigned short*)((char*)Pw + byte) = f2bf(p);
        }
#pragma unroll
    for (int mask = 1; mask < 16; mask <<= 1)
#pragma unroll
      for (int mf = 0; mf < 2; ++mf)
#pragma unroll
        for (int r = 0; r < 4; ++r)
          psum[mf][r] += __shfl_xor(psum[mf][r], mask, 64);

#pragma unroll
    for (int mf = 0; mf < 2; ++mf)
#pragma unroll
      for (int r = 0; r < 4; ++r)
        lrow[mf][r] = lrow[mf][r] * fac[mf][r] + psum[mf][r];

#pragma unroll
    for (int mf = 0; mf < 2; ++mf)
#pragma unroll
      for (int nf = 0; nf < 4; ++nf)
#pragma unroll
        for (int r = 0; r < 4; ++r) o[mf][nf][r] *= fac[mf][r];

    // PV: ctx[q][d] += P[q][kv] * V[kv][d]; P re-read in A-layout from swizzled LDS
#pragma unroll
    for (int ks = 0; ks < 2; ++ks) {
      bf16x8v pa[2], vf[4];
#pragma unroll
      for (int mf = 0; mf < 2; ++mf) {
        int q = mf * 16 + lr;
        unsigned byte = (unsigned)(q * 128 + ks * 64 + g * 16) ^ (unsigned)((q & 7) << 4);
        pa[mf] = *reinterpret_cast<const bf16x8v*>((const char*)Pw + byte);
      }
#pragma unroll
      for (int nf = 0; nf < 4; ++nf) {
        int d = nf * 16 + lr;
        unsigned byte = (unsigned)(d * 128 + ks * 64 + g * 16) ^ (unsigned)((d & 7) << 4);
        vf[nf] = *reinterpret_cast<const bf16x8v*>((const char*)Vs + byte);
      }
#pragma unroll
      for (int mf = 0; mf < 2; ++mf)
#pragma unroll
        for (int nf = 0; nf < 4; ++nf)
          o[mf][nf] = __builtin_amdgcn_mfma_f32_16x16x32_bf16(pa[mf], vf[nf], o[mf][nf], 0, 0, 0);
    }
    __syncthreads();
  }

  const int b_ = bh >> 4, h = bh & 15;
#pragma unroll
  for (int mf = 0; mf < 2; ++mf)
#pragma unroll
    for (int nf = 0; nf < 4; ++nf)
#pragma unroll
      for (int r = 0; r < 4; ++r) {
        int sr = q0 + mf * 16 + g * 4 + r;
        int d = nf * 16 + lr;
        float val = o[mf][nf][r] / lrow[mf][r];
        ctx[((size_t)b_ * SQ_LEN + sr) * E_DIM + h * D_DIM + d] = f2bf(val);
      }
}

__global__ __launch_bounds__(256)
void out_gemm(const unsigned short* __restrict__ cx,
              const unsigned short* __restrict__ wo,
              const float* __restrict__ ob,
              float* __restrict__ out) {
  const int mt = blockIdx.x, nt = blockIdx.y;

  __shared__ unsigned short As[128 * 64];
  __shared__ unsigned short Bs[128 * 64];

  const int t = threadIdx.x;
  const int lane = t & 63, wave = t >> 6;
  const int g = lane >> 4, lr = lane & 15;
  const int wr = (wave >> 1) * 64, wc = (wave & 1) * 64;
  const int m0 = mt * 128, n0 = nt * 128;

  const unsigned short* arow[4];
  const unsigned short* brow[4];
  int col[4];
#pragma unroll
  for (int i = 0; i < 4; ++i) {
    int f = i * 256 + t;
    int row = f >> 3, grp = f & 7;
    arow[i] = cx + (m0 + row) * E_DIM;
    brow[i] = wo + (n0 + row) * E_DIM;
    col[i] = (grp ^ (row & 7)) * 8;
  }

  f32x4 acc[4][4];
#pragma unroll
  for (int i = 0; i < 4; ++i)
#pragma unroll
    for (int j = 0; j < 4; ++j) acc[i][j] = f32x4{0.f, 0.f, 0.f, 0.f};

  for (int k0 = 0; k0 < E_DIM; k0 += 64) {
#pragma unroll
    for (int i = 0; i < 4; ++i) {
      unsigned ldsoff = (unsigned)((i * 256 + wave * 64) * 16);
      gload_lds16(arow[i] + k0 + col[i], (unsigned short*)((char*)As + ldsoff));
      gload_lds16(brow[i] + k0 + col[i], (unsigned short*)((char*)Bs + ldsoff));
    }
    __syncthreads();
#pragma unroll
    for (int ks = 0; ks < 2; ++ks) {
      bf16x8v a[4], b[4];
#pragma unroll
      for (int mf = 0; mf < 4; ++mf) {
        int row = wr + mf * 16 + lr;
        unsigned byte = (unsigned)(row * 128 + ks * 64 + g * 16) ^ (unsigned)((row & 7) << 4);
        a[mf] = *reinterpret_cast<const bf16x8v*>((const char*)As + byte);
      }
#pragma unroll
      for (int nf = 0; nf < 4; ++nf) {
        int row = wc + nf * 16 + lr;
        unsigned byte = (unsigned)(row * 128 + ks * 64 + g * 16) ^ (unsigned)((row & 7) << 4);
        b[nf] = *reinterpret_cast<const bf16x8v*>((const char*)Bs + byte);
      }
#pragma unroll
      for (int mf = 0; mf < 4; ++mf)
#pragma unroll
        for (int nf = 0; nf < 4; ++nf)
          acc[mf][nf] = __builtin_amdgcn_mfma_f32_16x16x32_bf16(a[mf], b[nf], acc[mf][nf], 0, 0, 0);
    }
    __syncthreads();
  }

#pragma unroll
  for (int mf = 0; mf < 4; ++mf) {
#pragma unroll
    for (int nf = 0; nf < 4; ++nf) {
      int n = n0 + wc + nf * 16 + lr;
      float bv = ob[n];
#pragma unroll
      for (int r = 0; r < 4; ++r) {
        int m = m0 + wr + mf * 16 + g * 4 + r;
        out[(size_t)m * E_DIM + n] = acc[mf][nf][r] + bv;
      }
    }
  }
}

extern "C" void kernel_launch(void* const* d_in, const int* in_sizes, int n_in,
                              void* d_out, int out_size, void* d_ws, size_t ws_size,
                              hipStream_t stream) {
  (void)in_sizes; (void)n_in; (void)out_size; (void)ws_size;
  const float* x     = (const float*)d_in[0];
  const float* cache = (const float*)d_in[1];
  const float* in_w  = (const float*)d_in[2];
  const float* in_b  = (const float*)d_in[3];
  const float* out_w = (const float*)d_in[4];
  const float* out_b = (const float*)d_in[5];
  float* out = (float*)d_out;

  char* ws = (char*)d_ws;
  unsigned short* xb   = (unsigned short*)(ws);                       // 8 MB  [2*2048,1024]
  unsigned short* cb   = (unsigned short*)(ws + (8u  << 20));         // 8 MB  [2*2048,1024]
  unsigned short* wqkv = (unsigned short*)(ws + (16u << 20));         // 6 MB  [3072,1024]
  unsigned short* wo   = (unsigned short*)(ws + (22u << 20));         // 2 MB  [1024,1024]
  unsigned short* Qb   = (unsigned short*)(ws + (24u << 20));         // 8 MB  [2,16,2048,64]
  unsigned short* Kb   = (unsigned short*)(ws + (32u << 20));         // 16 MB [2,16,4096,64]
  unsigned short* Vb   = (unsigned short*)(ws + (48u << 20));         // 16 MB [2,16,64,4096]
  unsigned short* cx   = (unsigned short*)(ws + (64u << 20));         // 8 MB  [2*2048,1024]

  convert_kernel<<<4096, 256, 0, stream>>>(x, xb, 2 * 2048 * 1024);
  convert_kernel<<<4096, 256, 0, stream>>>(cache, cb, 2 * 2048 * 1024);
  convert_kernel<<<3072, 256, 0, stream>>>(in_w, wqkv, 3 * 1024 * 1024);
  convert_kernel<<<1024, 256, 0, stream>>>(out_w, wo, 1024 * 1024);

  qkv_gemm<<<dim3(64, 8, 3), 256, 0, stream>>>(xb, cb, wqkv, in_b, Qb, Kb, Vb);
  attn_kernel<<<dim3(16, 32), 256, 0, stream>>>(Qb, Kb, Vb, cx);
  out_gemm<<<dim3(32, 8), 256, 0, stream>>>(cx, wo, out_b, out);
}

// Round 3
// 276.849 us; speedup vs baseline: 1.2041x; 1.2041x over previous
//
#include <hip/hip_runtime.h>
#include <stdint.h>

typedef __attribute__((ext_vector_type(4))) float f32x4;
typedef __attribute__((ext_vector_type(8))) __bf16 bf16x8v;

#define E_DIM 1024
#define H_NUM 16
#define D_DIM 64
#define SQ_LEN 2048
#define SKV_LEN 4096

static __device__ __forceinline__ unsigned short f2bf(float f) {
  union { float f; unsigned u; } v; v.f = f;
  unsigned u = v.u;
  u += 0x7fffu + ((u >> 16) & 1u);
  return (unsigned short)(u >> 16);
}

static __device__ __forceinline__ void gload_lds16(const unsigned short* g, unsigned short* l) {
  __builtin_amdgcn_global_load_lds(
      (const __attribute__((address_space(1))) unsigned int*)g,
      (__attribute__((address_space(3))) unsigned int*)l,
      16, 0, 0);
}

__global__ void convert_kernel(const float* __restrict__ in, unsigned short* __restrict__ out, int n) {
  int i = (blockIdx.x * blockDim.x + threadIdx.x) * 4;
  if (i >= n) return;
  const float4 f = *reinterpret_cast<const float4*>(in + i);
  ushort4 o;
  o.x = f2bf(f.x); o.y = f2bf(f.y); o.z = f2bf(f.z); o.w = f2bf(f.w);
  *reinterpret_cast<ushort4*>(out + i) = o;
}

// C[m][n] = sum_k A[m][k] * W[n][k]  (torch y = x @ W.T), 128x128 tile, BK=64.
// job 0: Q from x rows (M=4096), scaled by 0.125*log2(e)  [exp2-domain softmax]
// job 1: K from concat(cache,x) rows (M=8192), out [B,H,SKV,D]
// job 2: V same rows, out transposed [B,H,D,SKV]
__global__ __launch_bounds__(256)
void qkv_gemm(const unsigned short* __restrict__ xb,
              const unsigned short* __restrict__ cb,
              const unsigned short* __restrict__ wqkv,
              const float* __restrict__ in_b,
              unsigned short* __restrict__ Qo,
              unsigned short* __restrict__ Ko,
              unsigned short* __restrict__ Vo) {
  const int job = blockIdx.z;
  const int mt = blockIdx.x, nt = blockIdx.y;
  if (job == 0 && mt >= 32) return;

  __shared__ unsigned short As[128 * 64];
  __shared__ unsigned short Bs[128 * 64];

  const int t = threadIdx.x;
  const int lane = t & 63, wave = t >> 6;
  const int g = lane >> 4, lr = lane & 15;
  const int wr = (wave >> 1) * 64, wc = (wave & 1) * 64;
  const int m0 = mt * 128, n0 = nt * 128;

  const unsigned short* arow[4];
  const unsigned short* brow[4];
  int col[4];
  const unsigned short* wbase = wqkv + job * (E_DIM * E_DIM);
#pragma unroll
  for (int i = 0; i < 4; ++i) {
    int f = i * 256 + t;
    int row = f >> 3, grp = f & 7;
    int gm = m0 + row;
    const unsigned short* src;
    if (job == 0) {
      src = xb + gm * E_DIM;
    } else {
      int b = gm >> 12, s = gm & 4095;
      src = (s < 2048) ? (cb + (b * 2048 + s) * E_DIM)
                       : (xb + (b * 2048 + (s - 2048)) * E_DIM);
    }
    arow[i] = src;
    brow[i] = wbase + (n0 + row) * E_DIM;
    col[i] = (grp ^ (row & 7)) * 8;  // inverse-swizzled source granule (rule 21)
  }

  f32x4 acc[4][4];
#pragma unroll
  for (int i = 0; i < 4; ++i)
#pragma unroll
    for (int j = 0; j < 4; ++j) acc[i][j] = f32x4{0.f, 0.f, 0.f, 0.f};

  for (int k0 = 0; k0 < E_DIM; k0 += 64) {
#pragma unroll
    for (int i = 0; i < 4; ++i) {
      unsigned ldsoff = (unsigned)((i * 256 + wave * 64) * 16);
      gload_lds16(arow[i] + k0 + col[i], (unsigned short*)((char*)As + ldsoff));
      gload_lds16(brow[i] + k0 + col[i], (unsigned short*)((char*)Bs + ldsoff));
    }
    __syncthreads();
#pragma unroll
    for (int ks = 0; ks < 2; ++ks) {
      bf16x8v a[4], b[4];
#pragma unroll
      for (int mf = 0; mf < 4; ++mf) {
        int row = wr + mf * 16 + lr;
        unsigned byte = (unsigned)(row * 128 + ks * 64 + g * 16) ^ (unsigned)((row & 7) << 4);
        a[mf] = *reinterpret_cast<const bf16x8v*>((const char*)As + byte);
      }
#pragma unroll
      for (int nf = 0; nf < 4; ++nf) {
        int row = wc + nf * 16 + lr;
        unsigned byte = (unsigned)(row * 128 + ks * 64 + g * 16) ^ (unsigned)((row & 7) << 4);
        b[nf] = *reinterpret_cast<const bf16x8v*>((const char*)Bs + byte);
      }
#pragma unroll
      for (int mf = 0; mf < 4; ++mf)
#pragma unroll
        for (int nf = 0; nf < 4; ++nf)
          acc[mf][nf] = __builtin_amdgcn_mfma_f32_16x16x32_bf16(a[mf], b[nf], acc[mf][nf], 0, 0, 0);
    }
    __syncthreads();
  }

  const float* bptr = in_b + job * E_DIM;
  const float qscale = 0.125f * 1.44269504088896f;  // 1/sqrt(D) * log2(e)
#pragma unroll
  for (int mf = 0; mf < 4; ++mf) {
#pragma unroll
    for (int nf = 0; nf < 4; ++nf) {
      int n = n0 + wc + nf * 16 + lr;
      float bv = bptr[n];
      int h = n >> 6, d = n & 63;
#pragma unroll
      for (int r = 0; r < 4; ++r) {
        int m = m0 + wr + mf * 16 + g * 4 + r;
        float val = acc[mf][nf][r] + bv;
        if (job == 0) {
          int b = m >> 11, s = m & 2047;
          Qo[((b * H_NUM + h) * SQ_LEN + s) * D_DIM + d] = f2bf(val * qscale);
        } else if (job == 1) {
          int b = m >> 12, s = m & 4095;
          Ko[((b * H_NUM + h) * SKV_LEN + s) * D_DIM + d] = f2bf(val);
        } else {
          int b = m >> 12, s = m & 4095;
          Vo[((b * H_NUM + h) * D_DIM + d) * SKV_LEN + s] = f2bf(val);
        }
      }
    }
  }
}

// Flash attention, swapped-QK^T structure.
// Per block: 128 q-rows (4 waves x 32), KV tiles of 64, K/V double-buffered.
// S^T = mfma(K, Q): lane holds q = qf*16 + (lane&15), 16 kv values per qf ->
// row-reductions are in-lane trees + 2 shfl_xor. Stats (m, l) live in the
// lane domain; redistributed to the (g,r) accumulator domain only on rescale
// (rare, defer-max THR=8) and in the epilogue.
__global__ __launch_bounds__(256)
void attn_kernel(const unsigned short* __restrict__ Qb,
                 const unsigned short* __restrict__ Kb,
                 const unsigned short* __restrict__ Vb,
                 unsigned short* __restrict__ ctx) {
  const int qt = blockIdx.x;   // 16 q-tiles
  const int bh = blockIdx.y;   // 32 (b*16+h)

  __shared__ unsigned short Ks[2][64 * 64];
  __shared__ unsigned short Vs[2][64 * 64];
  __shared__ unsigned short Ps[4][32 * 64];

  const int t = threadIdx.x;
  const int lane = t & 63, wave = t >> 6;
  const int g = lane >> 4, lr = lane & 15;

  const unsigned short* Qh = Qb + (size_t)bh * SQ_LEN * D_DIM;
  const unsigned short* Kh = Kb + (size_t)bh * SKV_LEN * D_DIM;
  const unsigned short* Vh = Vb + (size_t)bh * D_DIM * SKV_LEN;

  const int q0 = qt * 128 + wave * 32;
  // Q as MFMA B-operand: lane holds col q = qf*16+lr, k = d = ks*32+g*8+j
  bf16x8v qfr[2][2];
#pragma unroll
  for (int qf = 0; qf < 2; ++qf)
#pragma unroll
    for (int ks = 0; ks < 2; ++ks)
      qfr[qf][ks] = *reinterpret_cast<const bf16x8v*>(Qh + (q0 + qf * 16 + lr) * D_DIM + ks * 32 + g * 8);

  f32x4 o[2][4];
#pragma unroll
  for (int qf = 0; qf < 2; ++qf)
#pragma unroll
    for (int df = 0; df < 4; ++df) o[qf][df] = f32x4{0.f, 0.f, 0.f, 0.f};
  float mrow[2] = {-1e30f, -1e30f};
  float lrow[2] = {0.f, 0.f};

  int srow[2], sgrp[2];
#pragma unroll
  for (int i = 0; i < 2; ++i) {
    int f = i * 256 + t;
    srow[i] = f >> 3;
    sgrp[i] = (f & 7) ^ (srow[i] & 7);
  }

  unsigned short* Pw = &Ps[wave][0];
  const int srcBase = (lane & 48) | ((lane >> 4) << 2);  // group base + q_local base

  // prologue: stage tile 0 into buffer 0
#pragma unroll
  for (int i = 0; i < 2; ++i) {
    unsigned ldsoff = (unsigned)((i * 256 + wave * 64) * 16);
    gload_lds16(Kh + srow[i] * D_DIM + sgrp[i] * 8, (unsigned short*)((char*)Ks[0] + ldsoff));
    gload_lds16(Vh + srow[i] * SKV_LEN + sgrp[i] * 8, (unsigned short*)((char*)Vs[0] + ldsoff));
  }
  __syncthreads();

  int cur = 0;
  for (int tkv = 0; tkv < SKV_LEN / 64; ++tkv) {
    // prefetch next tile into the other buffer (2-phase, T3-minimum)
    if (tkv + 1 < SKV_LEN / 64) {
      int kv0 = (tkv + 1) * 64;
#pragma unroll
      for (int i = 0; i < 2; ++i) {
        unsigned ldsoff = (unsigned)((i * 256 + wave * 64) * 16);
        gload_lds16(Kh + (kv0 + srow[i]) * D_DIM + sgrp[i] * 8, (unsigned short*)((char*)Ks[cur ^ 1] + ldsoff));
        gload_lds16(Vh + srow[i] * SKV_LEN + kv0 + sgrp[i] * 8, (unsigned short*)((char*)Vs[cur ^ 1] + ldsoff));
      }
    }

    // S^T = K @ Q : st[kvf][qf], col=lane&15 -> q, row=g*4+r -> kv
    f32x4 st[4][2];
#pragma unroll
    for (int kvf = 0; kvf < 4; ++kvf)
#pragma unroll
      for (int qf = 0; qf < 2; ++qf) st[kvf][qf] = f32x4{0.f, 0.f, 0.f, 0.f};
#pragma unroll
    for (int ks = 0; ks < 2; ++ks) {
      bf16x8v kf[4];
#pragma unroll
      for (int kvf = 0; kvf < 4; ++kvf) {
        int row = kvf * 16 + lr;
        unsigned byte = (unsigned)(row * 128 + ks * 64 + g * 16) ^ (unsigned)((row & 7) << 4);
        kf[kvf] = *reinterpret_cast<const bf16x8v*>((const char*)Ks[cur] + byte);
      }
#pragma unroll
      for (int kvf = 0; kvf < 4; ++kvf)
#pragma unroll
        for (int qf = 0; qf < 2; ++qf)
          st[kvf][qf] = __builtin_amdgcn_mfma_f32_16x16x32_bf16(kf[kvf], qfr[qf][ks], st[kvf][qf], 0, 0, 0);
    }

    // per-lane row max over 16 values, then cross-group (2 shfl)
    float pmax[2];
#pragma unroll
    for (int qf = 0; qf < 2; ++qf) {
      float a0 = fmaxf(fmaxf(st[0][qf][0], st[0][qf][1]), fmaxf(st[0][qf][2], st[0][qf][3]));
      float a1 = fmaxf(fmaxf(st[1][qf][0], st[1][qf][1]), fmaxf(st[1][qf][2], st[1][qf][3]));
      float a2 = fmaxf(fmaxf(st[2][qf][0], st[2][qf][1]), fmaxf(st[2][qf][2], st[2][qf][3]));
      float a3 = fmaxf(fmaxf(st[3][qf][0], st[3][qf][1]), fmaxf(st[3][qf][2], st[3][qf][3]));
      float m = fmaxf(fmaxf(a0, a1), fmaxf(a2, a3));
      m = fmaxf(m, __shfl_xor(m, 16, 64));
      m = fmaxf(m, __shfl_xor(m, 32, 64));
      pmax[qf] = m;
    }

    // defer-max (T13): rescale only if some row's max grew past THR (log2 units)
    float need = fmaxf(pmax[0] - mrow[0], pmax[1] - mrow[1]);
    if (!__all(need <= 8.0f)) {
#pragma unroll
      for (int qf = 0; qf < 2; ++qf) {
        float mn = fmaxf(mrow[qf], pmax[qf]);
        float fac = exp2f(mrow[qf] - mn);
        mrow[qf] = mn;
        lrow[qf] *= fac;
#pragma unroll
        for (int r = 0; r < 4; ++r) {
          float facr = __shfl(fac, srcBase + r, 64);
#pragma unroll
          for (int df = 0; df < 4; ++df) o[qf][df][r] *= facr;
        }
      }
    }

    // P = exp2(S^T - m), packed bf16 pair write
#pragma unroll
    for (int qf = 0; qf < 2; ++qf) {
      int q = qf * 16 + lr;
      float psum = 0.f;
#pragma unroll
      for (int kvf = 0; kvf < 4; ++kvf) {
        float p0 = exp2f(st[kvf][qf][0] - mrow[qf]);
        float p1 = exp2f(st[kvf][qf][1] - mrow[qf]);
        float p2 = exp2f(st[kvf][qf][2] - mrow[qf]);
        float p3 = exp2f(st[kvf][qf][3] - mrow[qf]);
        psum += (p0 + p1) + (p2 + p3);
        uint2 wv;
        wv.x = ((unsigned)f2bf(p1) << 16) | (unsigned)f2bf(p0);
        wv.y = ((unsigned)f2bf(p3) << 16) | (unsigned)f2bf(p2);
        unsigned byte = (unsigned)(q * 128 + kvf * 32 + g * 8) ^ (unsigned)((q & 7) << 4);
        *reinterpret_cast<uint2*>((char*)Pw + byte) = wv;
      }
      psum += __shfl_xor(psum, 16, 64);
      psum += __shfl_xor(psum, 32, 64);
      lrow[qf] += psum;
    }

    // PV: o[q][d] += P[q][kv] * V^T[d][kv]; P read back as A-frags (per-wave LDS, in-order)
#pragma unroll
    for (int ks = 0; ks < 2; ++ks) {
      bf16x8v pa[2], vf[4];
#pragma unroll
      for (int qf = 0; qf < 2; ++qf) {
        int q = qf * 16 + lr;
        unsigned byte = (unsigned)(q * 128 + ks * 64 + g * 16) ^ (unsigned)((q & 7) << 4);
        pa[qf] = *reinterpret_cast<const bf16x8v*>((const char*)Pw + byte);
      }
#pragma unroll
      for (int df = 0; df < 4; ++df) {
        int d = df * 16 + lr;
        unsigned byte = (unsigned)(d * 128 + ks * 64 + g * 16) ^ (unsigned)((d & 7) << 4);
        vf[df] = *reinterpret_cast<const bf16x8v*>((const char*)Vs[cur] + byte);
      }
#pragma unroll
      for (int qf = 0; qf < 2; ++qf)
#pragma unroll
        for (int df = 0; df < 4; ++df)
          o[qf][df] = __builtin_amdgcn_mfma_f32_16x16x32_bf16(pa[qf], vf[df], o[qf][df], 0, 0, 0);
    }
    __syncthreads();
    cur ^= 1;
  }

  const int b_ = bh >> 4, h = bh & 15;
#pragma unroll
  for (int qf = 0; qf < 2; ++qf) {
    float linv[4];
#pragma unroll
    for (int r = 0; r < 4; ++r)
      linv[r] = 1.0f / __shfl(lrow[qf], srcBase + r, 64);
#pragma unroll
    for (int df = 0; df < 4; ++df) {
#pragma unroll
      for (int r = 0; r < 4; ++r) {
        int sr = q0 + qf * 16 + g * 4 + r;
        int d = df * 16 + lr;
        ctx[((size_t)b_ * SQ_LEN + sr) * E_DIM + h * D_DIM + d] = f2bf(o[qf][df][r] * linv[r]);
      }
    }
  }
}

__global__ __launch_bounds__(256)
void out_gemm(const unsigned short* __restrict__ cx,
              const unsigned short* __restrict__ wo,
              const float* __restrict__ ob,
              float* __restrict__ out) {
  const int mt = blockIdx.x, nt = blockIdx.y;

  __shared__ unsigned short As[128 * 64];
  __shared__ unsigned short Bs[128 * 64];

  const int t = threadIdx.x;
  const int lane = t & 63, wave = t >> 6;
  const int g = lane >> 4, lr = lane & 15;
  const int wr = (wave >> 1) * 64, wc = (wave & 1) * 64;
  const int m0 = mt * 128, n0 = nt * 128;

  const unsigned short* arow[4];
  const unsigned short* brow[4];
  int col[4];
#pragma unroll
  for (int i = 0; i < 4; ++i) {
    int f = i * 256 + t;
    int row = f >> 3, grp = f & 7;
    arow[i] = cx + (m0 + row) * E_DIM;
    brow[i] = wo + (n0 + row) * E_DIM;
    col[i] = (grp ^ (row & 7)) * 8;
  }

  f32x4 acc[4][4];
#pragma unroll
  for (int i = 0; i < 4; ++i)
#pragma unroll
    for (int j = 0; j < 4; ++j) acc[i][j] = f32x4{0.f, 0.f, 0.f, 0.f};

  for (int k0 = 0; k0 < E_DIM; k0 += 64) {
#pragma unroll
    for (int i = 0; i < 4; ++i) {
      unsigned ldsoff = (unsigned)((i * 256 + wave * 64) * 16);
      gload_lds16(arow[i] + k0 + col[i], (unsigned short*)((char*)As + ldsoff));
      gload_lds16(brow[i] + k0 + col[i], (unsigned short*)((char*)Bs + ldsoff));
    }
    __syncthreads();
#pragma unroll
    for (int ks = 0; ks < 2; ++ks) {
      bf16x8v a[4], b[4];
#pragma unroll
      for (int mf = 0; mf < 4; ++mf) {
        int row = wr + mf * 16 + lr;
        unsigned byte = (unsigned)(row * 128 + ks * 64 + g * 16) ^ (unsigned)((row & 7) << 4);
        a[mf] = *reinterpret_cast<const bf16x8v*>((const char*)As + byte);
      }
#pragma unroll
      for (int nf = 0; nf < 4; ++nf) {
        int row = wc + nf * 16 + lr;
        unsigned byte = (unsigned)(row * 128 + ks * 64 + g * 16) ^ (unsigned)((row & 7) << 4);
        b[nf] = *reinterpret_cast<const bf16x8v*>((const char*)Bs + byte);
      }
#pragma unroll
      for (int mf = 0; mf < 4; ++mf)
#pragma unroll
        for (int nf = 0; nf < 4; ++nf)
          acc[mf][nf] = __builtin_amdgcn_mfma_f32_16x16x32_bf16(a[mf], b[nf], acc[mf][nf], 0, 0, 0);
    }
    __syncthreads();
  }

#pragma unroll
  for (int mf = 0; mf < 4; ++mf) {
#pragma unroll
    for (int nf = 0; nf < 4; ++nf) {
      int n = n0 + wc + nf * 16 + lr;
      float bv = ob[n];
#pragma unroll
      for (int r = 0; r < 4; ++r) {
        int m = m0 + wr + mf * 16 + g * 4 + r;
        out[(size_t)m * E_DIM + n] = acc[mf][nf][r] + bv;
      }
    }
  }
}

extern "C" void kernel_launch(void* const* d_in, const int* in_sizes, int n_in,
                              void* d_out, int out_size, void* d_ws, size_t ws_size,
                              hipStream_t stream) {
  (void)in_sizes; (void)n_in; (void)out_size; (void)ws_size;
  const float* x     = (const float*)d_in[0];
  const float* cache = (const float*)d_in[1];
  const float* in_w  = (const float*)d_in[2];
  const float* in_b  = (const float*)d_in[3];
  const float* out_w = (const float*)d_in[4];
  const float* out_b = (const float*)d_in[5];
  float* out = (float*)d_out;

  char* ws = (char*)d_ws;
  unsigned short* xb   = (unsigned short*)(ws);                       // 8 MB  [2*2048,1024]
  unsigned short* cb   = (unsigned short*)(ws + (8u  << 20));         // 8 MB  [2*2048,1024]
  unsigned short* wqkv = (unsigned short*)(ws + (16u << 20));         // 6 MB  [3072,1024]
  unsigned short* wo   = (unsigned short*)(ws + (22u << 20));         // 2 MB  [1024,1024]
  unsigned short* Qb   = (unsigned short*)(ws + (24u << 20));         // 8 MB  [2,16,2048,64]
  unsigned short* Kb   = (unsigned short*)(ws + (32u << 20));         // 16 MB [2,16,4096,64]
  unsigned short* Vb   = (unsigned short*)(ws + (48u << 20));         // 16 MB [2,16,64,4096]
  unsigned short* cx   = (unsigned short*)(ws + (64u << 20));         // 8 MB  [2*2048,1024]

  convert_kernel<<<4096, 256, 0, stream>>>(x, xb, 2 * 2048 * 1024);
  convert_kernel<<<4096, 256, 0, stream>>>(cache, cb, 2 * 2048 * 1024);
  convert_kernel<<<3072, 256, 0, stream>>>(in_w, wqkv, 3 * 1024 * 1024);
  convert_kernel<<<1024, 256, 0, stream>>>(out_w, wo, 1024 * 1024);

  qkv_gemm<<<dim3(64, 8, 3), 256, 0, stream>>>(xb, cb, wqkv, in_b, Qb, Kb, Vb);
  attn_kernel<<<dim3(16, 32), 256, 0, stream>>>(Qb, Kb, Vb, cx);
  out_gemm<<<dim3(32, 8), 256, 0, stream>>>(cx, wo, out_b, out);
}

// Round 4
// 248.585 us; speedup vs baseline: 1.3410x; 1.1137x over previous
//
#include <hip/hip_runtime.h>
#include <stdint.h>

typedef __attribute__((ext_vector_type(4))) float f32x4;
typedef __attribute__((ext_vector_type(8))) __bf16 bf16x8v;

#define E_DIM 1024
#define H_NUM 16
#define D_DIM 64
#define SQ_LEN 2048
#define SKV_LEN 4096

static __device__ __forceinline__ unsigned short f2bf(float f) {
  union { float f; unsigned u; } v; v.f = f;
  unsigned u = v.u;
  u += 0x7fffu + ((u >> 16) & 1u);
  return (unsigned short)(u >> 16);
}

static __device__ __forceinline__ unsigned cvt_pk_bf16(float lo, float hi) {
  unsigned r;
  asm("v_cvt_pk_bf16_f32 %0, %1, %2" : "=v"(r) : "v"(lo), "v"(hi));
  return r;
}

static __device__ __forceinline__ void gload_lds16(const unsigned short* g, unsigned short* l) {
  __builtin_amdgcn_global_load_lds(
      (const __attribute__((address_space(1))) unsigned int*)g,
      (__attribute__((address_space(3))) unsigned int*)l,
      16, 0, 0);
}

__global__ void convert_kernel(const float* __restrict__ in, unsigned short* __restrict__ out, int n) {
  int i = (blockIdx.x * blockDim.x + threadIdx.x) * 4;
  if (i >= n) return;
  const float4 f = *reinterpret_cast<const float4*>(in + i);
  ushort4 o;
  o.x = f2bf(f.x); o.y = f2bf(f.y); o.z = f2bf(f.z); o.w = f2bf(f.w);
  *reinterpret_cast<ushort4*>(out + i) = o;
}

// C[m][n] = sum_k A[m][k] * W[n][k]  (torch y = x @ W.T), 128x128 tile, BK=64.
// job 0: Q from x rows (M=4096), scaled by 0.125*log2(e)  [exp2-domain softmax]
// job 1: K from concat(cache,x) rows (M=8192), out [B,H,SKV,D]
// job 2: V same rows, out transposed [B,H,D,SKV]
__global__ __launch_bounds__(256)
void qkv_gemm(const unsigned short* __restrict__ xb,
              const unsigned short* __restrict__ cb,
              const unsigned short* __restrict__ wqkv,
              const float* __restrict__ in_b,
              unsigned short* __restrict__ Qo,
              unsigned short* __restrict__ Ko,
              unsigned short* __restrict__ Vo) {
  const int job = blockIdx.z;
  const int mt = blockIdx.x, nt = blockIdx.y;
  if (job == 0 && mt >= 32) return;

  __shared__ unsigned short As[128 * 64];
  __shared__ unsigned short Bs[128 * 64];

  const int t = threadIdx.x;
  const int lane = t & 63, wave = t >> 6;
  const int g = lane >> 4, lr = lane & 15;
  const int wr = (wave >> 1) * 64, wc = (wave & 1) * 64;
  const int m0 = mt * 128, n0 = nt * 128;

  const unsigned short* arow[4];
  const unsigned short* brow[4];
  int col[4];
  const unsigned short* wbase = wqkv + job * (E_DIM * E_DIM);
#pragma unroll
  for (int i = 0; i < 4; ++i) {
    int f = i * 256 + t;
    int row = f >> 3, grp = f & 7;
    int gm = m0 + row;
    const unsigned short* src;
    if (job == 0) {
      src = xb + gm * E_DIM;
    } else {
      int b = gm >> 12, s = gm & 4095;
      src = (s < 2048) ? (cb + (b * 2048 + s) * E_DIM)
                       : (xb + (b * 2048 + (s - 2048)) * E_DIM);
    }
    arow[i] = src;
    brow[i] = wbase + (n0 + row) * E_DIM;
    col[i] = (grp ^ (row & 7)) * 8;  // inverse-swizzled source granule (rule 21)
  }

  f32x4 acc[4][4];
#pragma unroll
  for (int i = 0; i < 4; ++i)
#pragma unroll
    for (int j = 0; j < 4; ++j) acc[i][j] = f32x4{0.f, 0.f, 0.f, 0.f};

  for (int k0 = 0; k0 < E_DIM; k0 += 64) {
#pragma unroll
    for (int i = 0; i < 4; ++i) {
      unsigned ldsoff = (unsigned)((i * 256 + wave * 64) * 16);
      gload_lds16(arow[i] + k0 + col[i], (unsigned short*)((char*)As + ldsoff));
      gload_lds16(brow[i] + k0 + col[i], (unsigned short*)((char*)Bs + ldsoff));
    }
    __syncthreads();
#pragma unroll
    for (int ks = 0; ks < 2; ++ks) {
      bf16x8v a[4], b[4];
#pragma unroll
      for (int mf = 0; mf < 4; ++mf) {
        int row = wr + mf * 16 + lr;
        unsigned byte = (unsigned)(row * 128 + ks * 64 + g * 16) ^ (unsigned)((row & 7) << 4);
        a[mf] = *reinterpret_cast<const bf16x8v*>((const char*)As + byte);
      }
#pragma unroll
      for (int nf = 0; nf < 4; ++nf) {
        int row = wc + nf * 16 + lr;
        unsigned byte = (unsigned)(row * 128 + ks * 64 + g * 16) ^ (unsigned)((row & 7) << 4);
        b[nf] = *reinterpret_cast<const bf16x8v*>((const char*)Bs + byte);
      }
#pragma unroll
      for (int mf = 0; mf < 4; ++mf)
#pragma unroll
        for (int nf = 0; nf < 4; ++nf)
          acc[mf][nf] = __builtin_amdgcn_mfma_f32_16x16x32_bf16(a[mf], b[nf], acc[mf][nf], 0, 0, 0);
    }
    __syncthreads();
  }

  const float* bptr = in_b + job * E_DIM;
  const float qscale = 0.125f * 1.44269504088896f;  // 1/sqrt(D) * log2(e)
#pragma unroll
  for (int mf = 0; mf < 4; ++mf) {
#pragma unroll
    for (int nf = 0; nf < 4; ++nf) {
      int n = n0 + wc + nf * 16 + lr;
      float bv = bptr[n];
      int h = n >> 6, d = n & 63;
#pragma unroll
      for (int r = 0; r < 4; ++r) {
        int m = m0 + wr + mf * 16 + g * 4 + r;
        float val = acc[mf][nf][r] + bv;
        if (job == 0) {
          int b = m >> 11, s = m & 2047;
          Qo[((b * H_NUM + h) * SQ_LEN + s) * D_DIM + d] = f2bf(val * qscale);
        } else if (job == 1) {
          int b = m >> 12, s = m & 4095;
          Ko[((b * H_NUM + h) * SKV_LEN + s) * D_DIM + d] = f2bf(val);
        } else {
          int b = m >> 12, s = m & 4095;
          Vo[((b * H_NUM + h) * D_DIM + d) * SKV_LEN + s] = f2bf(val);
        }
      }
    }
  }
}

// Flash attention, swapped-QK^T structure.
// Per block: 128 q-rows (4 waves x 32), KV tiles of 64, K/V double-buffered.
// st = S - m_old directly (accumulator init = -m, m0 = 0).
// l accumulated via MFMA with ones-B (lands in (g,r) domain, no shfl).
// P packed with v_cvt_pk_bf16_f32.
__global__ __launch_bounds__(256)
void attn_kernel(const unsigned short* __restrict__ Qb,
                 const unsigned short* __restrict__ Kb,
                 const unsigned short* __restrict__ Vb,
                 unsigned short* __restrict__ ctx) {
  const int qt = blockIdx.x;   // 16 q-tiles
  const int bh = blockIdx.y;   // 32 (b*16+h)

  __shared__ unsigned short Ks[2][64 * 64];
  __shared__ unsigned short Vs[2][64 * 64];
  __shared__ unsigned short Ps[4][32 * 64];

  const int t = threadIdx.x;
  const int lane = t & 63, wave = t >> 6;
  const int g = lane >> 4, lr = lane & 15;

  const unsigned short* Qh = Qb + (size_t)bh * SQ_LEN * D_DIM;
  const unsigned short* Kh = Kb + (size_t)bh * SKV_LEN * D_DIM;
  const unsigned short* Vh = Vb + (size_t)bh * D_DIM * SKV_LEN;

  const int q0 = qt * 128 + wave * 32;
  bf16x8v qfr[2][2];
#pragma unroll
  for (int qf = 0; qf < 2; ++qf)
#pragma unroll
    for (int ks = 0; ks < 2; ++ks)
      qfr[qf][ks] = *reinterpret_cast<const bf16x8v*>(Qh + (q0 + qf * 16 + lr) * D_DIM + ks * 32 + g * 8);

  const __bf16 one = (__bf16)1.0f;
  const bf16x8v ones = {one, one, one, one, one, one, one, one};

  f32x4 o[2][4];
  f32x4 lacc[2];
#pragma unroll
  for (int qf = 0; qf < 2; ++qf) {
#pragma unroll
    for (int df = 0; df < 4; ++df) o[qf][df] = f32x4{0.f, 0.f, 0.f, 0.f};
    lacc[qf] = f32x4{0.f, 0.f, 0.f, 0.f};
  }
  float mrow[2] = {0.f, 0.f};   // running max in log2 units; scores ~N(0,1.4) so m=0 start is safe

  int srow[2], sgrp[2];
#pragma unroll
  for (int i = 0; i < 2; ++i) {
    int f = i * 256 + t;
    srow[i] = f >> 3;
    sgrp[i] = (f & 7) ^ (srow[i] & 7);
  }

  unsigned short* Pw = &Ps[wave][0];
  const int srcBase = (lane & 48) | ((lane >> 4) << 2);  // same-group lane holding row g*4+r

  // prologue: stage tile 0 into buffer 0
#pragma unroll
  for (int i = 0; i < 2; ++i) {
    unsigned ldsoff = (unsigned)((i * 256 + wave * 64) * 16);
    gload_lds16(Kh + srow[i] * D_DIM + sgrp[i] * 8, (unsigned short*)((char*)Ks[0] + ldsoff));
    gload_lds16(Vh + srow[i] * SKV_LEN + sgrp[i] * 8, (unsigned short*)((char*)Vs[0] + ldsoff));
  }
  __syncthreads();

  int cur = 0;
  for (int tkv = 0; tkv < SKV_LEN / 64; ++tkv) {
    // prefetch next tile into the other buffer
    if (tkv + 1 < SKV_LEN / 64) {
      int kv0 = (tkv + 1) * 64;
#pragma unroll
      for (int i = 0; i < 2; ++i) {
        unsigned ldsoff = (unsigned)((i * 256 + wave * 64) * 16);
        gload_lds16(Kh + (kv0 + srow[i]) * D_DIM + sgrp[i] * 8, (unsigned short*)((char*)Ks[cur ^ 1] + ldsoff));
        gload_lds16(Vh + srow[i] * SKV_LEN + kv0 + sgrp[i] * 8, (unsigned short*)((char*)Vs[cur ^ 1] + ldsoff));
      }
    }

    // st = K @ Q - m_old  (C-init = -m). col=lane&15 -> q, row=g*4+r -> kv
    f32x4 st[4][2];
#pragma unroll
    for (int kvf = 0; kvf < 4; ++kvf)
#pragma unroll
      for (int qf = 0; qf < 2; ++qf)
        st[kvf][qf] = f32x4{-mrow[qf], -mrow[qf], -mrow[qf], -mrow[qf]};
#pragma unroll
    for (int ks = 0; ks < 2; ++ks) {
      bf16x8v kf[4];
#pragma unroll
      for (int kvf = 0; kvf < 4; ++kvf) {
        int row = kvf * 16 + lr;
        unsigned byte = (unsigned)(row * 128 + ks * 64 + g * 16) ^ (unsigned)((row & 7) << 4);
        kf[kvf] = *reinterpret_cast<const bf16x8v*>((const char*)Ks[cur] + byte);
      }
      __builtin_amdgcn_s_setprio(1);
#pragma unroll
      for (int kvf = 0; kvf < 4; ++kvf)
#pragma unroll
        for (int qf = 0; qf < 2; ++qf)
          st[kvf][qf] = __builtin_amdgcn_mfma_f32_16x16x32_bf16(kf[kvf], qfr[qf][ks], st[kvf][qf], 0, 0, 0);
      __builtin_amdgcn_s_setprio(0);
    }

    // row max of st (= S - m_old): in-lane tree + 2 shfl
    float pmax[2];
#pragma unroll
    for (int qf = 0; qf < 2; ++qf) {
      float m = st[0][qf][0];
      m = fmaxf(m, st[0][qf][1]); m = fmaxf(m, st[0][qf][2]); m = fmaxf(m, st[0][qf][3]);
#pragma unroll
      for (int kvf = 1; kvf < 4; ++kvf) {
        m = fmaxf(m, st[kvf][qf][0]); m = fmaxf(m, st[kvf][qf][1]);
        m = fmaxf(m, st[kvf][qf][2]); m = fmaxf(m, st[kvf][qf][3]);
      }
      m = fmaxf(m, __shfl_xor(m, 16, 64));
      m = fmaxf(m, __shfl_xor(m, 32, 64));
      pmax[qf] = m;
    }

    // defer-max (T13): only rescale when some row grew past THR=8 (log2 units)
    float need = fmaxf(pmax[0], pmax[1]);
    if (!__all(need <= 8.0f)) {
#pragma unroll
      for (int qf = 0; qf < 2; ++qf) {
        float dq = fmaxf(pmax[qf], 0.f);
        float fac = exp2f(-dq);
        mrow[qf] += dq;
#pragma unroll
        for (int kvf = 0; kvf < 4; ++kvf)
#pragma unroll
          for (int j = 0; j < 4; ++j) st[kvf][qf][j] -= dq;
#pragma unroll
        for (int r = 0; r < 4; ++r) {
          float facr = __shfl(fac, srcBase + r, 64);
          lacc[qf][r] *= facr;
#pragma unroll
          for (int df = 0; df < 4; ++df) o[qf][df][r] *= facr;
        }
      }
    }

    // P = exp2(st), cvt_pk pack, LDS write
#pragma unroll
    for (int qf = 0; qf < 2; ++qf) {
      int q = qf * 16 + lr;
#pragma unroll
      for (int kvf = 0; kvf < 4; ++kvf) {
        float p0 = exp2f(st[kvf][qf][0]);
        float p1 = exp2f(st[kvf][qf][1]);
        float p2 = exp2f(st[kvf][qf][2]);
        float p3 = exp2f(st[kvf][qf][3]);
        uint2 wv;
        wv.x = cvt_pk_bf16(p0, p1);
        wv.y = cvt_pk_bf16(p2, p3);
        unsigned byte = (unsigned)(q * 128 + kvf * 32 + g * 8) ^ (unsigned)((q & 7) << 4);
        *reinterpret_cast<uint2*>((char*)Pw + byte) = wv;
      }
    }

    // PV: o += P * V^T ; l += P * 1 (MFMA row-sum, lands in (g,r) domain)
#pragma unroll
    for (int ks = 0; ks < 2; ++ks) {
      bf16x8v pa[2], vf[4];
#pragma unroll
      for (int qf = 0; qf < 2; ++qf) {
        int q = qf * 16 + lr;
        unsigned byte = (unsigned)(q * 128 + ks * 64 + g * 16) ^ (unsigned)((q & 7) << 4);
        pa[qf] = *reinterpret_cast<const bf16x8v*>((const char*)Pw + byte);
      }
#pragma unroll
      for (int df = 0; df < 4; ++df) {
        int d = df * 16 + lr;
        unsigned byte = (unsigned)(d * 128 + ks * 64 + g * 16) ^ (unsigned)((d & 7) << 4);
        vf[df] = *reinterpret_cast<const bf16x8v*>((const char*)Vs[cur] + byte);
      }
      __builtin_amdgcn_s_setprio(1);
#pragma unroll
      for (int qf = 0; qf < 2; ++qf) {
        lacc[qf] = __builtin_amdgcn_mfma_f32_16x16x32_bf16(pa[qf], ones, lacc[qf], 0, 0, 0);
#pragma unroll
        for (int df = 0; df < 4; ++df)
          o[qf][df] = __builtin_amdgcn_mfma_f32_16x16x32_bf16(pa[qf], vf[df], o[qf][df], 0, 0, 0);
      }
      __builtin_amdgcn_s_setprio(0);
    }
    __syncthreads();
    cur ^= 1;
  }

  const int b_ = bh >> 4, h = bh & 15;
#pragma unroll
  for (int qf = 0; qf < 2; ++qf) {
    float linv[4];
#pragma unroll
    for (int r = 0; r < 4; ++r) linv[r] = 1.0f / lacc[qf][r];
#pragma unroll
    for (int df = 0; df < 4; ++df) {
#pragma unroll
      for (int r = 0; r < 4; ++r) {
        int sr = q0 + qf * 16 + g * 4 + r;
        int d = df * 16 + lr;
        ctx[((size_t)b_ * SQ_LEN + sr) * E_DIM + h * D_DIM + d] = f2bf(o[qf][df][r] * linv[r]);
      }
    }
  }
}

__global__ __launch_bounds__(256)
void out_gemm(const unsigned short* __restrict__ cx,
              const unsigned short* __restrict__ wo,
              const float* __restrict__ ob,
              float* __restrict__ out) {
  const int mt = blockIdx.x, nt = blockIdx.y;

  __shared__ unsigned short As[128 * 64];
  __shared__ unsigned short Bs[128 * 64];

  const int t = threadIdx.x;
  const int lane = t & 63, wave = t >> 6;
  const int g = lane >> 4, lr = lane & 15;
  const int wr = (wave >> 1) * 64, wc = (wave & 1) * 64;
  const int m0 = mt * 128, n0 = nt * 128;

  const unsigned short* arow[4];
  const unsigned short* brow[4];
  int col[4];
#pragma unroll
  for (int i = 0; i < 4; ++i) {
    int f = i * 256 + t;
    int row = f >> 3, grp = f & 7;
    arow[i] = cx + (m0 + row) * E_DIM;
    brow[i] = wo + (n0 + row) * E_DIM;
    col[i] = (grp ^ (row & 7)) * 8;
  }

  f32x4 acc[4][4];
#pragma unroll
  for (int i = 0; i < 4; ++i)
#pragma unroll
    for (int j = 0; j < 4; ++j) acc[i][j] = f32x4{0.f, 0.f, 0.f, 0.f};

  for (int k0 = 0; k0 < E_DIM; k0 += 64) {
#pragma unroll
    for (int i = 0; i < 4; ++i) {
      unsigned ldsoff = (unsigned)((i * 256 + wave * 64) * 16);
      gload_lds16(arow[i] + k0 + col[i], (unsigned short*)((char*)As + ldsoff));
      gload_lds16(brow[i] + k0 + col[i], (unsigned short*)((char*)Bs + ldsoff));
    }
    __syncthreads();
#pragma unroll
    for (int ks = 0; ks < 2; ++ks) {
      bf16x8v a[4], b[4];
#pragma unroll
      for (int mf = 0; mf < 4; ++mf) {
        int row = wr + mf * 16 + lr;
        unsigned byte = (unsigned)(row * 128 + ks * 64 + g * 16) ^ (unsigned)((row & 7) << 4);
        a[mf] = *reinterpret_cast<const bf16x8v*>((const char*)As + byte);
      }
#pragma unroll
      for (int nf = 0; nf < 4; ++nf) {
        int row = wc + nf * 16 + lr;
        unsigned byte = (unsigned)(row * 128 + ks * 64 + g * 16) ^ (unsigned)((row & 7) << 4);
        b[nf] = *reinterpret_cast<const bf16x8v*>((const char*)Bs + byte);
      }
#pragma unroll
      for (int mf = 0; mf < 4; ++mf)
#pragma unroll
        for (int nf = 0; nf < 4; ++nf)
          acc[mf][nf] = __builtin_amdgcn_mfma_f32_16x16x32_bf16(a[mf], b[nf], acc[mf][nf], 0, 0, 0);
    }
    __syncthreads();
  }

#pragma unroll
  for (int mf = 0; mf < 4; ++mf) {
#pragma unroll
    for (int nf = 0; nf < 4; ++nf) {
      int n = n0 + wc + nf * 16 + lr;
      float bv = ob[n];
#pragma unroll
      for (int r = 0; r < 4; ++r) {
        int m = m0 + wr + mf * 16 + g * 4 + r;
        out[(size_t)m * E_DIM + n] = acc[mf][nf][r] + bv;
      }
    }
  }
}

extern "C" void kernel_launch(void* const* d_in, const int* in_sizes, int n_in,
                              void* d_out, int out_size, void* d_ws, size_t ws_size,
                              hipStream_t stream) {
  (void)in_sizes; (void)n_in; (void)out_size; (void)ws_size;
  const float* x     = (const float*)d_in[0];
  const float* cache = (const float*)d_in[1];
  const float* in_w  = (const float*)d_in[2];
  const float* in_b  = (const float*)d_in[3];
  const float* out_w = (const float*)d_in[4];
  const float* out_b = (const float*)d_in[5];
  float* out = (float*)d_out;

  char* ws = (char*)d_ws;
  unsigned short* xb   = (unsigned short*)(ws);                       // 8 MB  [2*2048,1024]
  unsigned short* cb   = (unsigned short*)(ws + (8u  << 20));         // 8 MB  [2*2048,1024]
  unsigned short* wqkv = (unsigned short*)(ws + (16u << 20));         // 6 MB  [3072,1024]
  unsigned short* wo   = (unsigned short*)(ws + (22u << 20));         // 2 MB  [1024,1024]
  unsigned short* Qb   = (unsigned short*)(ws + (24u << 20));         // 8 MB  [2,16,2048,64]
  unsigned short* Kb   = (unsigned short*)(ws + (32u << 20));         // 16 MB [2,16,4096,64]
  unsigned short* Vb   = (unsigned short*)(ws + (48u << 20));         // 16 MB [2,16,64,4096]
  unsigned short* cx   = (unsigned short*)(ws + (64u << 20));         // 8 MB  [2*2048,1024]

  convert_kernel<<<4096, 256, 0, stream>>>(x, xb, 2 * 2048 * 1024);
  convert_kernel<<<4096, 256, 0, stream>>>(cache, cb, 2 * 2048 * 1024);
  convert_kernel<<<3072, 256, 0, stream>>>(in_w, wqkv, 3 * 1024 * 1024);
  convert_kernel<<<1024, 256, 0, stream>>>(out_w, wo, 1024 * 1024);

  qkv_gemm<<<dim3(64, 8, 3), 256, 0, stream>>>(xb, cb, wqkv, in_b, Qb, Kb, Vb);
  attn_kernel<<<dim3(16, 32), 256, 0, stream>>>(Qb, Kb, Vb, cx);
  out_gemm<<<dim3(32, 8), 256, 0, stream>>>(cx, wo, out_b, out);
}